// Round 8
// baseline (102.740 us; speedup 1.0000x reference)
//
#include <hip/hip_runtime.h>

typedef float f32x16 __attribute__((ext_vector_type(16)));
typedef int v8i __attribute__((ext_vector_type(8)));

#define NUM_EMB 8192
#define DIM 64
#define NTOK 32768
#define TOKS_PER_BLOCK 128
#define TOK_BLOCKS 256            // 32768 / 128 -> 1 block per CU
#define SUPER 64                  // 64 super-chunks x 128 entries
#define SUPER_BYTES 8192          // 128 entries x 64 B (fp8 fragments)

#define B_SCALE (-8192.0f)        // -2 * 4096
#define SCORE_BIAS 128.0f         // scores in (36,220) -> positive -> uint-monotone

__device__ __forceinline__ unsigned umin2(unsigned a, unsigned b) { return a < b ? a : b; }

// ---------------------------------------------------------------------------
// Prep (128 blocks x 256 = 32768 threads): build fp8 B fragments.
// uint4 slot m = (c*2+h)*64 + lane, bytes b: f = 2h + (b>>3), j = b&7,
//   n = c*32 + (lane&31), k = f*16 + (lane>>5)*8 + j, val = e4m3(-8192*W[n][k]).
// Chunk c occupies bytes [c*2048, (c+1)*2048) lane-linearly -> super-chunk s
// (4 chunks) is the contiguous 8 KB at s*8192: perfect for global_load_lds.
// ---------------------------------------------------------------------------
__global__ __launch_bounds__(256) void vq_prep(const float* __restrict__ weight,
                                               uint4* __restrict__ wsB,
                                               float* __restrict__ loss_out) {
  int m = blockIdx.x * 256 + threadIdx.x;   // 0..32767
  if (m == 0)
    __hip_atomic_store(loss_out, 0.0f, __ATOMIC_RELAXED, __HIP_MEMORY_SCOPE_AGENT);
  int lane = m & 63, h = (m >> 6) & 1, c = m >> 7;
  int n = c * 32 + (lane & 31);
  int kb = (lane >> 5) * 8;
  const float* p = weight + n * DIM;
  unsigned r[4];
#pragma unroll
  for (int q = 0; q < 2; ++q) {
    const float* pk = p + (2 * h + q) * 16 + kb;
    int lo = __builtin_amdgcn_cvt_pk_fp8_f32(B_SCALE * pk[0], B_SCALE * pk[1], 0, false);
    lo     = __builtin_amdgcn_cvt_pk_fp8_f32(B_SCALE * pk[2], B_SCALE * pk[3], lo, true);
    int hi = __builtin_amdgcn_cvt_pk_fp8_f32(B_SCALE * pk[4], B_SCALE * pk[5], 0, false);
    hi     = __builtin_amdgcn_cvt_pk_fp8_f32(B_SCALE * pk[6], B_SCALE * pk[7], hi, true);
    r[q * 2] = (unsigned)lo; r[q * 2 + 1] = (unsigned)hi;
  }
  wsB[m] = make_uint4(r[0], r[1], r[2], r[3]);
}

// ---------------------------------------------------------------------------
// Main: 256 blocks (1/CU) x 1024 threads (16 waves = 4 token-rows x 4 entry-
// slices). Block owns 128 tokens, scans all 8192 entries as 64 super-chunks
// of 128. Per round: waves 0..7 DMA the next 8 KB super-chunk into the LDS
// double buffer (global_load_lds width=16); every wave does ONE K=64 scaled
// MFMA from LDS + 32 key-update VALU. B is read from L2 once per CU per
// super-chunk (128 MB total vs 512 MB in R7).
// ---------------------------------------------------------------------------
__global__ __launch_bounds__(1024) void vq_main(const float* __restrict__ z_e,
                                                const float* __restrict__ weight,
                                                const uint4* __restrict__ wsB,
                                                float* __restrict__ out,
                                                float* __restrict__ loss_out) {
  __shared__ unsigned char lds_a[TOKS_PER_BLOCK * 72];   // 9216 B (8B pad/row)
  __shared__ unsigned char bbuf[2][SUPER_BYTES];         // 16 KB double buffer
  __shared__ unsigned lds_part[4][TOKS_PER_BLOCK];       // per entry-slice mins
  __shared__ unsigned lds_tok[TOKS_PER_BLOCK];
  __shared__ float wsum[16];

  const int tid  = threadIdx.x;
  const int lane = tid & 63;
  const int wv   = tid >> 6;          // 0..15
  const int row4 = wv & 3;            // token tile-row
  const int g    = wv >> 2;           // entry slice within super-chunk
  const int half = lane >> 5;
  const int ln31 = lane & 31;
  const int tbase = blockIdx.x * TOKS_PER_BLOCK;

  const unsigned char* wsb_bytes = reinterpret_cast<const unsigned char*>(wsB);

  // ---- stage A: 128 tokens (32 KB fp32 -> 8 KB fp8) into LDS ----
  {
    int token = tid >> 3, q8 = tid & 7;               // 8 floats per thread
    const float* p = z_e + (size_t)(tbase + token) * DIM + q8 * 8;
    float4 x0 = *reinterpret_cast<const float4*>(p);
    float4 x1 = *reinterpret_cast<const float4*>(p + 4);
    int lo = __builtin_amdgcn_cvt_pk_fp8_f32(x0.x, x0.y, 0, false);
    lo     = __builtin_amdgcn_cvt_pk_fp8_f32(x0.z, x0.w, lo, true);
    int hi = __builtin_amdgcn_cvt_pk_fp8_f32(x1.x, x1.y, 0, false);
    hi     = __builtin_amdgcn_cvt_pk_fp8_f32(x1.z, x1.w, hi, true);
    *reinterpret_cast<uint2*>(&lds_a[token * 72 + q8 * 8]) = make_uint2((unsigned)lo, (unsigned)hi);
  }
  // ---- stage B super-chunk 0 (waves 0..7, 1 KB each) ----
  if (wv < 8) {
    const unsigned char* src = wsb_bytes + 0 * SUPER_BYTES + wv * 1024 + lane * 16;
    __builtin_amdgcn_global_load_lds(
        (const __attribute__((address_space(1))) void*)src,
        (__attribute__((address_space(3))) void*)&bbuf[0][wv * 1024], 16, 0, 0);
  }
  __syncthreads();

  // ---- A fragment (K=64): token = row4*32 + ln31, byte b: k=(b>>3)*16+half*8+(b&7) ----
  v8i a8;
  {
    union { uint2 d2[4]; v8i v; } au;
#pragma unroll
    for (int f = 0; f < 4; ++f)
      au.d2[f] = *reinterpret_cast<const uint2*>(&lds_a[(row4 * 32 + ln31) * 72 + f * 16 + half * 8]);
    a8 = au.v;
  }

  f32x16 bias;
#pragma unroll
  for (int i = 0; i < 16; ++i) bias[i] = SCORE_BIAS;

  unsigned run[16];
#pragma unroll
  for (int i = 0; i < 16; ++i) run[i] = 0xFFFFFFFFu;

  unsigned idx = (unsigned)(g * 32 + ln31);

  for (int t = 0; t < SUPER; ++t) {
    int p = t & 1;
    if (wv < 8) {   // stage super-chunk t+1 into the other buffer (padded read at t=63)
      const unsigned char* src = wsb_bytes + (size_t)(t + 1) * SUPER_BYTES + wv * 1024 + lane * 16;
      __builtin_amdgcn_global_load_lds(
          (const __attribute__((address_space(1))) void*)src,
          (__attribute__((address_space(3))) void*)&bbuf[1 - p][wv * 1024], 16, 0, 0);
    }

    union { uint4 q[2]; v8i v; } bu;
    bu.q[0] = *reinterpret_cast<const uint4*>(&bbuf[p][g * 2048 + (lane << 4)]);
    bu.q[1] = *reinterpret_cast<const uint4*>(&bbuf[p][g * 2048 + 1024 + (lane << 4)]);

    f32x16 acc = __builtin_amdgcn_mfma_scale_f32_32x32x64_f8f6f4(
        a8, bu.v, bias, 0 /*fmtA=fp8*/, 0 /*fmtB=fp8*/, 0, 0x7F, 0, 0x7F);

#pragma unroll
    for (int i = 0; i < 16; ++i)
      run[i] = umin2(run[i], (__float_as_uint(acc[i]) & 0xFFFFE000u) | idx);
    idx += 128;

    __syncthreads();  // staged t+1 complete; all reads of bbuf[p] done
  }

  // ---- in-place butterfly argmin over the 32 entry-columns of this slice ----
#pragma unroll
  for (int i = 0; i < 16; ++i) {
    unsigned v = run[i];
    v = umin2(v, (unsigned)__builtin_amdgcn_ds_swizzle((int)v, 0x041F));
    v = umin2(v, (unsigned)__builtin_amdgcn_ds_swizzle((int)v, 0x081F));
    v = umin2(v, (unsigned)__builtin_amdgcn_ds_swizzle((int)v, 0x101F));
    v = umin2(v, (unsigned)__builtin_amdgcn_ds_swizzle((int)v, 0x201F));
    v = umin2(v, (unsigned)__builtin_amdgcn_ds_swizzle((int)v, 0x401F));
    run[i] = v;
  }

  // C/D layout (32x32): col = lane&31, row = (reg&3) + 8*(reg>>2) + 4*half
  if (ln31 == 0) {
#pragma unroll
    for (int reg = 0; reg < 16; ++reg) {
      int row = (reg & 3) + 8 * (reg >> 2) + 4 * half;
      lds_part[g][row4 * 32 + row] = run[reg];
    }
  }
  __syncthreads();

  if (tid < TOKS_PER_BLOCK) {
    unsigned k = umin2(umin2(lds_part[0][tid], lds_part[1][tid]),
                       umin2(lds_part[2][tid], lds_part[3][tid]));
    lds_tok[tid] = k & 0x1FFFu;
  }
  __syncthreads();

  // ---- gather (exact fp32), straight-through output, loss ----
  const float4* z4 = reinterpret_cast<const float4*>(z_e);
  const float4* w4 = reinterpret_cast<const float4*>(weight);
  float4* o4 = reinterpret_cast<float4*>(out);
  float lsum = 0.0f;
#pragma unroll
  for (int r = 0; r < 2; ++r) {
    int gg = r * 1024 + tid;             // 0..2047 float4s = 128 tokens x 64 dims
    int t = gg >> 4, q = gg & 15;
    float4 z = z4[(size_t)tbase * 16 + gg];
    float4 w = w4[(size_t)lds_tok[t] * 16 + q];
    float4 o;
    o.x = z.x + (w.x - z.x); o.y = z.y + (w.y - z.y);
    o.z = z.z + (w.z - z.z); o.w = z.w + (w.w - z.w);
    o4[(size_t)tbase * 16 + gg] = o;
    float dx = z.x - w.x, dy = z.y - w.y, dz = z.z - w.z, dw = z.w - w.w;
    lsum += dx * dx + dy * dy + dz * dz + dw * dw;
  }
#pragma unroll
  for (int s = 32; s >= 1; s >>= 1) lsum += __shfl_xor(lsum, s, 64);
  if (lane == 0) wsum[wv] = lsum;
  __syncthreads();
  if (tid == 0) {
    float tot = 0.0f;
#pragma unroll
    for (int i = 0; i < 16; ++i) tot += wsum[i];
    atomicAdd(loss_out, tot * (1.25f / 2097152.0f));
  }
}

extern "C" void kernel_launch(void* const* d_in, const int* in_sizes, int n_in,
                              void* d_out, int out_size, void* d_ws, size_t ws_size,
                              hipStream_t stream) {
  const float* z_e    = (const float*)d_in[0];
  const float* weight = (const float*)d_in[1];
  float* out  = (float*)d_out;
  float* loss = out + (out_size - 1);   // last element = vq_loss
  uint4* wsB = (uint4*)d_ws;            // 512 KB fp8 B fragments (+8 KB pad read)

  vq_prep<<<128, 256, 0, stream>>>(weight, wsB, loss);
  vq_main<<<TOK_BLOCKS, 1024, 0, stream>>>(z_e, weight, wsB, out, loss);
}

// Round 9
// 93.304 us; speedup vs baseline: 1.1011x; 1.1011x over previous
//
#include <hip/hip_runtime.h>

typedef float f32x16 __attribute__((ext_vector_type(16)));
typedef int v8i __attribute__((ext_vector_type(8)));

#define NUM_EMB 8192
#define DIM 64
#define NTOK 32768
#define TOKS_PER_BLOCK 32
#define TOK_BLOCKS 1024          // 32768 / 32
#define WAVES 8                  // 512-thread blocks
#define CHUNKS_PER_WAVE 32       // 256 chunks / 8 waves

#define B_SCALE (-8192.0f)       // -2 * 4096
#define SCORE_BIAS 128.0f        // scores in (36,220) -> positive -> uint-monotone

__device__ __forceinline__ unsigned umin2(unsigned a, unsigned b) { return a < b ? a : b; }

// ---------------------------------------------------------------------------
// Prep (128 blocks x 256 = 32768 threads): build fp8 B fragments.
// uint4 slot m = (c*2+h)*64 + lane, bytes b: f = 2h + (b>>3), j = b&7,
//   n = c*32 + (lane&31), k = f*16 + (lane>>5)*8 + j, val = e4m3(-8192*W[n][k]).
// Byte->k map matches the A fragments, so any HW k-permutation cancels.
// ---------------------------------------------------------------------------
__global__ __launch_bounds__(256) void vq_prep(const float* __restrict__ weight,
                                               uint4* __restrict__ wsB,
                                               float* __restrict__ loss_out) {
  int m = blockIdx.x * 256 + threadIdx.x;   // 0..32767
  if (m == 0)
    __hip_atomic_store(loss_out, 0.0f, __ATOMIC_RELAXED, __HIP_MEMORY_SCOPE_AGENT);
  int lane = m & 63, h = (m >> 6) & 1, c = m >> 7;
  int n = c * 32 + (lane & 31);
  int kb = (lane >> 5) * 8;
  const float* p = weight + n * DIM;
  unsigned r[4];
#pragma unroll
  for (int q = 0; q < 2; ++q) {
    const float* pk = p + (2 * h + q) * 16 + kb;
    int lo = __builtin_amdgcn_cvt_pk_fp8_f32(B_SCALE * pk[0], B_SCALE * pk[1], 0, false);
    lo     = __builtin_amdgcn_cvt_pk_fp8_f32(B_SCALE * pk[2], B_SCALE * pk[3], lo, true);
    int hi = __builtin_amdgcn_cvt_pk_fp8_f32(B_SCALE * pk[4], B_SCALE * pk[5], 0, false);
    hi     = __builtin_amdgcn_cvt_pk_fp8_f32(B_SCALE * pk[6], B_SCALE * pk[7], hi, true);
    r[q * 2] = (unsigned)lo; r[q * 2 + 1] = (unsigned)hi;
  }
  wsB[m] = make_uint4(r[0], r[1], r[2], r[3]);
}

// ---------------------------------------------------------------------------
// Main: 1024 blocks x 512 threads (8 waves). Block owns 32 tokens; wave wv
// scans chunks [wv*32, wv*32+32) of 32 entries each: ONE independent K=64
// scaled MFMA + 32 key-update VALU per chunk, depth-2 register prefetch.
// NO per-chunk barriers. 8-way LDS merge, in-block epilogue.
// ---------------------------------------------------------------------------
__global__ __launch_bounds__(512) void vq_main(const float* __restrict__ z_e,
                                               const float* __restrict__ weight,
                                               const uint4* __restrict__ wsB,
                                               float* __restrict__ out,
                                               float* __restrict__ loss_out) {
  __shared__ unsigned char lds_a[TOKS_PER_BLOCK * 72];   // 8B pad per token row
  __shared__ unsigned lds_part[WAVES][TOKS_PER_BLOCK];
  __shared__ unsigned lds_tok[TOKS_PER_BLOCK];
  __shared__ float wsum[WAVES];

  const int tid  = threadIdx.x;
  const int lane = tid & 63;
  const int wv   = tid >> 6;          // 0..7
  const int half = lane >> 5;
  const int ln31 = lane & 31;
  const int tbase = blockIdx.x * TOKS_PER_BLOCK;

  // ---- stage A: 32 tokens (2048 floats) -> fp8 LDS; 4 floats/thread ----
  {
    int token = tid >> 4, q4 = tid & 15;
    const float* p = z_e + (size_t)(tbase + token) * DIM + q4 * 4;
    float4 x = *reinterpret_cast<const float4*>(p);
    int v = __builtin_amdgcn_cvt_pk_fp8_f32(x.x, x.y, 0, false);
    v     = __builtin_amdgcn_cvt_pk_fp8_f32(x.z, x.w, v, true);
    *reinterpret_cast<unsigned*>(&lds_a[token * 72 + q4 * 4]) = (unsigned)v;
  }
  __syncthreads();

  // ---- A fragment (K=64): token = ln31, byte b: k = (b>>3)*16 + half*8 + (b&7) ----
  v8i a8;
  {
    union { uint2 d2[4]; v8i v; } au;
#pragma unroll
    for (int f = 0; f < 4; ++f)
      au.d2[f] = *reinterpret_cast<const uint2*>(&lds_a[ln31 * 72 + f * 16 + half * 8]);
    a8 = au.v;
  }

  f32x16 bias;
#pragma unroll
  for (int i = 0; i < 16; ++i) bias[i] = SCORE_BIAS;

  unsigned run[16];
#pragma unroll
  for (int i = 0; i < 16; ++i) run[i] = 0xFFFFFFFFu;

  const int c0 = wv * CHUNKS_PER_WAVE;
  unsigned idx = (unsigned)(c0 * 32 + ln31);

  // chunk c -> uint4 indices c*128 + lane (h=0) and c*128 + 64 + lane (h=1)
  uint4 bufA[2], bufB[2];
  bufA[0] = wsB[(c0 + 0) * 128 + lane];
  bufB[0] = wsB[(c0 + 0) * 128 + 64 + lane];
  bufA[1] = wsB[(c0 + 1) * 128 + lane];
  bufB[1] = wsB[(c0 + 1) * 128 + 64 + lane];

#pragma unroll 2
  for (int c = 0; c < CHUNKS_PER_WAVE; ++c) {
    uint4 curA = bufA[c & 1], curB = bufB[c & 1];
    int cn = c0 + c + 2;                     // depth-2 prefetch (2-chunk pad read)
    bufA[c & 1] = wsB[cn * 128 + lane];
    bufB[c & 1] = wsB[cn * 128 + 64 + lane];

    union { uint4 q[2]; v8i v; } bu;
    bu.q[0] = curA; bu.q[1] = curB;

    f32x16 acc = __builtin_amdgcn_mfma_scale_f32_32x32x64_f8f6f4(
        a8, bu.v, bias, 0 /*fmtA=fp8*/, 0 /*fmtB=fp8*/, 0, 0x7F, 0, 0x7F);

#pragma unroll
    for (int i = 0; i < 16; ++i)
      run[i] = umin2(run[i], (__float_as_uint(acc[i]) & 0xFFFFE000u) | idx);
    idx += 32;
  }

  // ---- in-place butterfly argmin over the 32 entry-columns ----
#pragma unroll
  for (int i = 0; i < 16; ++i) {
    unsigned v = run[i];
    v = umin2(v, (unsigned)__builtin_amdgcn_ds_swizzle((int)v, 0x041F));
    v = umin2(v, (unsigned)__builtin_amdgcn_ds_swizzle((int)v, 0x081F));
    v = umin2(v, (unsigned)__builtin_amdgcn_ds_swizzle((int)v, 0x101F));
    v = umin2(v, (unsigned)__builtin_amdgcn_ds_swizzle((int)v, 0x201F));
    v = umin2(v, (unsigned)__builtin_amdgcn_ds_swizzle((int)v, 0x401F));
    run[i] = v;
  }

  // C/D layout (32x32): col = lane&31, row = (reg&3) + 8*(reg>>2) + 4*half
  if (ln31 == 0) {
#pragma unroll
    for (int reg = 0; reg < 16; ++reg) {
      int row = (reg & 3) + 8 * (reg >> 2) + 4 * half;
      lds_part[wv][row] = run[reg];
    }
  }
  __syncthreads();

  if (tid < TOKS_PER_BLOCK) {
    unsigned k = lds_part[0][tid];
#pragma unroll
    for (int w = 1; w < WAVES; ++w) k = umin2(k, lds_part[w][tid]);
    lds_tok[tid] = k & 0x1FFFu;
  }
  __syncthreads();

  // ---- gather (exact fp32), straight-through output, loss ----
  {
    int g = tid;                        // 0..511 float4s = 32 tokens x 64 dims
    int t = g >> 4, q = g & 15;
    float4 z = reinterpret_cast<const float4*>(z_e)[(size_t)tbase * 16 + g];
    float4 w = reinterpret_cast<const float4*>(weight)[(size_t)lds_tok[t] * 16 + q];
    float4 o;
    o.x = z.x + (w.x - z.x); o.y = z.y + (w.y - z.y);
    o.z = z.z + (w.z - z.z); o.w = z.w + (w.w - z.w);
    reinterpret_cast<float4*>(out)[(size_t)tbase * 16 + g] = o;
    float dx = z.x - w.x, dy = z.y - w.y, dz = z.z - w.z, dw = z.w - w.w;
    float lsum = dx * dx + dy * dy + dz * dz + dw * dw;
#pragma unroll
    for (int s = 32; s >= 1; s >>= 1) lsum += __shfl_xor(lsum, s, 64);
    if (lane == 0) wsum[wv] = lsum;
  }
  __syncthreads();
  if (tid == 0) {
    float tot = 0.0f;
#pragma unroll
    for (int i = 0; i < WAVES; ++i) tot += wsum[i];
    atomicAdd(loss_out, tot * (1.25f / 2097152.0f));
  }
}

extern "C" void kernel_launch(void* const* d_in, const int* in_sizes, int n_in,
                              void* d_out, int out_size, void* d_ws, size_t ws_size,
                              hipStream_t stream) {
  const float* z_e    = (const float*)d_in[0];
  const float* weight = (const float*)d_in[1];
  float* out  = (float*)d_out;
  float* loss = out + (out_size - 1);   // last element = vq_loss
  uint4* wsB = (uint4*)d_ws;            // 512 KB fp8 B fragments (+4 KB pad read)

  vq_prep<<<128, 256, 0, stream>>>(weight, wsB, loss);
  vq_main<<<TOK_BLOCKS, 512, 0, stream>>>(z_e, weight, wsB, out, loss);
}